// Round 17
// baseline (302.552 us; speedup 1.0000x reference)
//
#include <hip/hip_runtime.h>
#include <hip/hip_bf16.h>

using f32x4  = __attribute__((ext_vector_type(4))) float;
using i32x4  = __attribute__((ext_vector_type(4))) int;
using bf16x8 = __attribute__((ext_vector_type(8))) short;
using bf16x4 = __attribute__((ext_vector_type(4))) short;
using f16x4  = __attribute__((ext_vector_type(4))) _Float16;

constexpr int BATCH = 8, SEQ = 1024, DIM = 768, NHEAD = 12, HDIM = 64;
constexpr int MROWS = BATCH * SEQ;   // 8192

__device__ __forceinline__ short f2bf(float f) {
    union { float f; unsigned u; } x; x.f = f;
    unsigned r = (x.u + 0x7fffu + ((x.u >> 16) & 1u)) >> 16;
    return (short)r;
}
__device__ __forceinline__ float fexp2(float x) { return __builtin_amdgcn_exp2f(x); }

// async global->LDS, 16B per lane; LDS dest = wave-uniform base + lane*16
__device__ __forceinline__ void gload_lds16(const void* g, void* l) {
    __builtin_amdgcn_global_load_lds(
        (const __attribute__((address_space(1))) void*)g,
        (__attribute__((address_space(3))) void*)l, 16, 0, 0);
}

__device__ __forceinline__ bf16x8 cvt8(const float* p) {
    const f32x4 x0 = *(const f32x4*)p;
    const f32x4 x1 = *(const f32x4*)(p + 4);
    bf16x8 r;
    #pragma unroll
    for (int j = 0; j < 4; ++j) { r[j] = f2bf(x0[j]); r[4 + j] = f2bf(x1[j]); }
    return r;
}

// K fragment-order: attn reads kb[c][ks] at tile4k*4096 + c*1024 + ks*512 + lane*8
__device__ __forceinline__ long kfrag_addr(int tok, int dd) {
    return ((long)(tok >> 6)) * 4096 + ((tok & 63) >> 4) * 1024 + (dd >> 5) * 512
         + ((dd >> 3) & 3) * 128 + (tok & 15) * 8 + (dd & 7);
}
// V fragment-order: attn reads vb[df][ks] at tile4k*4096 + df*1024 + ks*512 + lane*8
__device__ __forceinline__ long vfrag_addr(int tok, int dd) {
    return ((long)(tok >> 6)) * 4096 + (dd >> 4) * 1024 + ((tok >> 5) & 1) * 512
         + ((tok >> 3) & 3) * 128 + (dd & 15) * 8 + (tok & 7);
}

// single fp32->bf16 prepass
__global__ __launch_bounds__(256)
void cvt_all(const float* __restrict__ q, const float* __restrict__ k,
             const float* __restrict__ v,
             const float* __restrict__ Wq, const float* __restrict__ Wk,
             const float* __restrict__ Wv, const float* __restrict__ Wo,
             short* __restrict__ qb, short* __restrict__ kb, short* __restrict__ vb,
             short* __restrict__ Wqb, short* __restrict__ Wkb,
             short* __restrict__ Wvb, short* __restrict__ Wob,
             int nbig8, int nsml8) {
    const int stride = gridDim.x * 256;
    for (int i = blockIdx.x * 256 + threadIdx.x; i < nbig8; i += stride) {
        const long base = (long)i * 8;
        *(bf16x8*)(qb + base) = cvt8(q + base);
        *(bf16x8*)(kb + base) = cvt8(k + base);
        *(bf16x8*)(vb + base) = cvt8(v + base);
    }
    for (int i = blockIdx.x * 256 + threadIdx.x; i < nsml8; i += stride) {
        const long base = (long)i * 8;
        *(bf16x8*)(Wqb + base) = cvt8(Wq + base);
        *(bf16x8*)(Wkb + base) = cvt8(Wk + base);
        *(bf16x8*)(Wvb + base) = cvt8(Wv + base);
        *(bf16x8*)(Wob + base) = cvt8(Wo + base);
    }
}

// Fused Q/K/V projection (round-13): 128x128 tile, global_load_lds width=16.
__global__ __launch_bounds__(256, 4)
void gemm_qkv(const short* __restrict__ qb, const short* __restrict__ kb,
              const short* __restrict__ vbp,
              const short* __restrict__ Wqb, const short* __restrict__ Wkb,
              const short* __restrict__ Wvb,
              const float* __restrict__ bq, const float* __restrict__ bk,
              const float* __restrict__ bv,
              short* __restrict__ Qp, short* __restrict__ Kp, short* __restrict__ Vp) {
    constexpr int K  = DIM;
    constexpr int NT = DIM / 128;
    __shared__ alignas(16) short As[128][32];
    __shared__ alignas(16) short Bs[128][32];

    const int sub = blockIdx.x % 3;
    const int bid = blockIdx.x / 3;
    const short* A = sub == 0 ? qb : sub == 1 ? kb : vbp;
    const short* W = sub == 0 ? Wqb : sub == 1 ? Wkb : Wvb;
    const float* bias = sub == 0 ? bq : sub == 1 ? bk : bv;

    const int bm = bid / NT, bn = bid % NT;
    const int m0 = bm * 128, n0 = bn * 128;
    const int t = threadIdx.x;
    const int lane = t & 63, w = t >> 6;
    const int wm = (w >> 1) * 64, wn = (w & 1) * 64;
    const int l16 = lane & 15, lg = lane >> 4;

    const int lrow = lane >> 2, lcol = (lane & 3) * 8;
    const short* ag = A + (long)(m0 + w * 32 + lrow) * K + lcol;
    const short* wg = W + (long)(n0 + w * 32 + lrow) * K + lcol;
    short* lA0 = &As[w * 32][0];
    short* lA1 = &As[w * 32 + 16][0];
    short* lB0 = &Bs[w * 32][0];
    short* lB1 = &Bs[w * 32 + 16][0];

    f32x4 acc[4][4] = {};

    for (int k0 = 0; k0 < K; k0 += 32) {
        gload_lds16(ag + k0, lA0);
        gload_lds16(ag + (long)16 * K + k0, lA1);
        gload_lds16(wg + k0, lB0);
        gload_lds16(wg + (long)16 * K + k0, lB1);
        __syncthreads();

        bf16x8 af[4], bfg[4];
        const int kc = lg * 8;
        #pragma unroll
        for (int mi = 0; mi < 4; ++mi)
            af[mi] = *(const bf16x8*)&As[wm + mi * 16 + l16][kc];
        #pragma unroll
        for (int ni = 0; ni < 4; ++ni)
            bfg[ni] = *(const bf16x8*)&Bs[wn + ni * 16 + l16][kc];
        #pragma unroll
        for (int mi = 0; mi < 4; ++mi)
            #pragma unroll
            for (int ni = 0; ni < 4; ++ni)
                acc[mi][ni] = __builtin_amdgcn_mfma_f32_16x16x32_bf16(
                    af[mi], bfg[ni], acc[mi][ni], 0, 0, 0);
        __syncthreads();
    }

    #pragma unroll
    for (int mi = 0; mi < 4; ++mi) {
        const int row = m0 + wm + mi * 16 + lg * 4;
        const int bb = row / SEQ;
        #pragma unroll
        for (int ni = 0; ni < 4; ++ni) {
            const int col = n0 + wn + ni * 16 + l16;
            const float bv = bias[col];
            const int hh = col >> 6, dd = col & 63;
            #pragma unroll
            for (int j = 0; j < 4; ++j) {
                float val = acc[mi][ni][j] + bv;
                if (sub == 0) {
                    Qp[(long)(row + j) * DIM + col] = f2bf(val * 0.125f);
                } else {
                    const int tok = (row % SEQ) + j;
                    const long pbase = (long)(bb * NHEAD + hh) * 65536;
                    if (sub == 1)
                        Kp[pbase + kfrag_addr(tok, dd)] = f2bf(val);
                    else
                        Vp[pbase + vfrag_addr(tok, dd)] = f2bf(val);
                }
            }
        }
    }
}

// Output projection (round-13): 128x128 tile, global_load_lds staging.
__global__ __launch_bounds__(256, 4)
void gemm_out(const short* __restrict__ A, const short* __restrict__ W,
              const float* __restrict__ bias, float* __restrict__ Cout) {
    constexpr int K  = DIM;
    constexpr int NT = DIM / 128;
    __shared__ alignas(16) short As[128][32];
    __shared__ alignas(16) short Bs[128][32];

    const int bm = blockIdx.x / NT, bn = blockIdx.x % NT;
    const int m0 = bm * 128, n0 = bn * 128;
    const int t = threadIdx.x;
    const int lane = t & 63, w = t >> 6;
    const int wm = (w >> 1) * 64, wn = (w & 1) * 64;
    const int l16 = lane & 15, lg = lane >> 4;

    const int lrow = lane >> 2, lcol = (lane & 3) * 8;
    const short* ag = A + (long)(m0 + w * 32 + lrow) * K + lcol;
    const short* wg = W + (long)(n0 + w * 32 + lrow) * K + lcol;
    short* lA0 = &As[w * 32][0];
    short* lA1 = &As[w * 32 + 16][0];
    short* lB0 = &Bs[w * 32][0];
    short* lB1 = &Bs[w * 32 + 16][0];

    f32x4 acc[4][4] = {};

    for (int k0 = 0; k0 < K; k0 += 32) {
        gload_lds16(ag + k0, lA0);
        gload_lds16(ag + (long)16 * K + k0, lA1);
        gload_lds16(wg + k0, lB0);
        gload_lds16(wg + (long)16 * K + k0, lB1);
        __syncthreads();

        bf16x8 af[4], bfg[4];
        const int kc = lg * 8;
        #pragma unroll
        for (int mi = 0; mi < 4; ++mi)
            af[mi] = *(const bf16x8*)&As[wm + mi * 16 + l16][kc];
        #pragma unroll
        for (int ni = 0; ni < 4; ++ni)
            bfg[ni] = *(const bf16x8*)&Bs[wn + ni * 16 + l16][kc];
        #pragma unroll
        for (int mi = 0; mi < 4; ++mi)
            #pragma unroll
            for (int ni = 0; ni < 4; ++ni)
                acc[mi][ni] = __builtin_amdgcn_mfma_f32_16x16x32_bf16(
                    af[mi], bfg[ni], acc[mi][ni], 0, 0, 0);
        __syncthreads();
    }

    #pragma unroll
    for (int mi = 0; mi < 4; ++mi) {
        const int row = m0 + wm + mi * 16 + lg * 4;
        #pragma unroll
        for (int ni = 0; ni < 4; ++ni) {
            const int col = n0 + wn + ni * 16 + l16;
            const float bv = bias[col];
            #pragma unroll
            for (int j = 0; j < 4; ++j)
                Cout[(long)(row + j) * DIM + col] = acc[mi][ni][j] + bv;
        }
    }
}

// Flash attention, KVBLK=128: 8 iterations (half the barrier/reduce/fixed
// overhead of KVBLK=64). fp16 double-buffered masked-bias LDS [2][64][136],
// mask loaded sync at write (L3-hot), bias reg-prefetched, P aliased into
// CUR rows (272B row >= 256B of P), T13 defer-max.
__global__ __launch_bounds__(256, 4)
void attn_kernel(const short* __restrict__ Qp, const short* __restrict__ Kt,
                 const short* __restrict__ Vt, const float* __restrict__ bias,
                 const int* __restrict__ mask, short* __restrict__ Op) {
    __shared__ _Float16 Bsm[2][64][136];   // 34.8 KB

    const int d = blockIdx.x;
    const int lgc = (d & 7) * 192 + (d >> 3);   // XCD-contiguous (b,h) pairs
    const int qt = lgc & 15, pair = lgc >> 4;
    const int h = pair % NHEAD, b = pair / NHEAD;

    const int t = threadIdx.x, lane = t & 63, w = t >> 6;
    const int l16 = lane & 15, lg = lane >> 4;
    const int ql = w * 16 + l16;

    const int qrow = qt * 64 + ql;
    const short* qptr = Qp + (long)(b * SEQ + qrow) * DIM + h * HDIM + lg * 8;
    const bf16x8 qf0 = *(const bf16x8*)qptr;
    const bf16x8 qf1 = *(const bf16x8*)(qptr + 32);

    const short* ktile = Kt + (long)pair * 65536 + lane * 8;
    const short* vtile = Vt + (long)pair * 65536 + lane * 8;

    const int srow = t >> 4, scol = (t & 15) * 4;
    const float* bst = bias + ((long)pair * SEQ + qt * 64 + srow) * SEQ + scol;
    const int*   mst = mask + ((long)b * SEQ + qt * 64 + srow) * SEQ + scol;

    f32x4 acc_o[4] = {};
    float m_run = -1e30f, l_run = 0.f;
    constexpr float L2E = 1.4426950408889634f;

    f32x4 br[8];   // bias prefetch: 64x128 tile = 8 f32x4/thread

    auto issue_bm = [&](int kt) {     // kt in 128-key tiles
        #pragma unroll
        for (int i = 0; i < 4; ++i) {
            br[i]     = __builtin_nontemporal_load((const f32x4*)(bst + (long)i * 16 * SEQ + kt * 128));
            br[4 + i] = __builtin_nontemporal_load((const f32x4*)(bst + (long)i * 16 * SEQ + kt * 128 + 64));
        }
    };
    auto write_bm = [&](int buf, int kt) {
        #pragma unroll
        for (int half = 0; half < 2; ++half)
            #pragma unroll
            for (int i = 0; i < 4; ++i) {
                const i32x4 mr = *(const i32x4*)(mst + (long)i * 16 * SEQ + kt * 128 + half * 64);
                f16x4 o;
                #pragma unroll
                for (int j = 0; j < 4; ++j)
                    o[j] = (_Float16)(mr[j] ? br[half * 4 + i][j] : -30000.0f);
                *(f16x4*)&Bsm[buf][i * 16 + srow][half * 64 + scol] = o;
            }
    };

    auto compute = [&](int kt, int buf) {
        const short* kf = ktile + kt * 8192;   // two consecutive 4K-tiles
        const short* vf = vtile + kt * 8192;
        short* prow = (short*)&Bsm[buf][ql][0];

        f32x4 s[8];
        __builtin_amdgcn_s_setprio(1);
        #pragma unroll
        for (int c = 0; c < 8; ++c) {
            const long off = (c >> 2) * 4096 + (c & 3) * 1024;
            const bf16x8 kb0 = *(const bf16x8*)(kf + off);
            const f16x4 cv = *(const f16x4*)&Bsm[buf][ql][c * 16 + lg * 4];
            f32x4 ci;
            #pragma unroll
            for (int j = 0; j < 4; ++j) ci[j] = (float)cv[j];
            s[c] = __builtin_amdgcn_mfma_f32_16x16x32_bf16(kb0, qf0, ci, 0, 0, 0);
        }
        #pragma unroll
        for (int c = 0; c < 8; ++c) {
            const long off = (c >> 2) * 4096 + (c & 3) * 1024 + 512;
            const bf16x8 kb1 = *(const bf16x8*)(kf + off);
            s[c] = __builtin_amdgcn_mfma_f32_16x16x32_bf16(kb1, qf1, s[c], 0, 0, 0);
        }
        __builtin_amdgcn_s_setprio(0);

        float mc[8];
        #pragma unroll
        for (int c = 0; c < 8; ++c)
            mc[c] = fmaxf(fmaxf(s[c][0], s[c][1]), fmaxf(s[c][2], s[c][3]));
        float mt = fmaxf(fmaxf(fmaxf(mc[0], mc[1]), fmaxf(mc[2], mc[3])),
                         fmaxf(fmaxf(mc[4], mc[5]), fmaxf(mc[6], mc[7])));
        mt = fmaxf(mt, __shfl_xor(mt, 16));
        mt = fmaxf(mt, __shfl_xor(mt, 32));

        if (!__all(mt - m_run <= 8.f)) {
            const float mn = fmaxf(m_run, mt);
            const float alpha = fexp2((m_run - mn) * L2E);
            m_run = mn;
            float al[4];
            #pragma unroll
            for (int j = 0; j < 4; ++j) al[j] = __shfl(alpha, lg * 4 + j);
            #pragma unroll
            for (int df = 0; df < 4; ++df)
                #pragma unroll
                for (int j = 0; j < 4; ++j)
                    acc_o[df][j] *= al[j];
            l_run *= alpha;
        }
        const float nm = -m_run * L2E;

        float lt = 0.f;
        #pragma unroll
        for (int c = 0; c < 8; ++c) {
            bf16x4 pk;
            #pragma unroll
            for (int j = 0; j < 4; ++j) {
                const float e = fexp2(fmaf(s[c][j], L2E, nm));
                lt += e;
                pk[j] = f2bf(e);
            }
            *(bf16x4*)(prow + c * 16 + lg * 4) = pk;
        }
        lt += __shfl_xor(lt, 16);
        lt += __shfl_xor(lt, 32);
        l_run += lt;

        bf16x8 pa[4];
        #pragma unroll
        for (int ks = 0; ks < 4; ++ks)
            pa[ks] = *(const bf16x8*)(prow + ks * 32 + lg * 8);

        __builtin_amdgcn_s_setprio(1);
        #pragma unroll
        for (int df = 0; df < 4; ++df)
            #pragma unroll
            for (int ks = 0; ks < 4; ++ks) {
                const bf16x8 vb = *(const bf16x8*)(vf + (ks >> 1) * 4096 + df * 1024 + (ks & 1) * 512);
                acc_o[df] = __builtin_amdgcn_mfma_f32_16x16x32_bf16(pa[ks], vb, acc_o[df], 0, 0, 0);
            }
        __builtin_amdgcn_s_setprio(0);
    };

    issue_bm(0);
    write_bm(0, 0);
    issue_bm(1);
    __syncthreads();

    int cur = 0;
    for (int kt = 0; kt < 8; ++kt) {
        compute(kt, cur);
        if (kt < 7) {
            write_bm(cur ^ 1, kt + 1);     // bias regs issued a full iter ago
            if (kt < 6) issue_bm(kt + 2);  // next-next bias: full-iter cover
            __syncthreads();
            cur ^= 1;
        }
    }

    float linv[4];
    #pragma unroll
    for (int j = 0; j < 4; ++j)
        linv[j] = 1.f / fmaxf(__shfl(l_run, lg * 4 + j), 1e-20f);

    #pragma unroll
    for (int df = 0; df < 4; ++df) {
        #pragma unroll
        for (int j = 0; j < 4; ++j) {
            const float val = acc_o[df][j] * linv[j];
            const int row = b * SEQ + qt * 64 + w * 16 + lg * 4 + j;
            const int col = h * HDIM + df * 16 + l16;
            Op[(long)row * DIM + col] = f2bf(val);
        }
    }
}

extern "C" void kernel_launch(void* const* d_in, const int* in_sizes, int n_in,
                              void* d_out, int out_size, void* d_ws, size_t ws_size,
                              hipStream_t stream) {
    const float* q         = (const float*)d_in[0];
    const float* k         = (const float*)d_in[1];
    const float* v         = (const float*)d_in[2];
    const float* attn_bias = (const float*)d_in[3];
    const int*   attn_mask = (const int*)d_in[4];
    const float* Wq = (const float*)d_in[5];
    const float* bq = (const float*)d_in[6];
    const float* Wk = (const float*)d_in[7];
    const float* bk = (const float*)d_in[8];
    const float* Wv = (const float*)d_in[9];
    const float* bv = (const float*)d_in[10];
    const float* Wo = (const float*)d_in[11];
    const float* bo = (const float*)d_in[12];
    float* out = (float*)d_out;

    const long NED = (long)MROWS * DIM;       // 6291456
    const long WED = (long)DIM * DIM;         // 589824
    short* Qp  = (short*)d_ws;                // [8192][768] bf16, pre-scaled 1/8
    short* Kp  = Qp + NED;                    // K fragment-order [96][16][4096]
    short* Vp  = Kp + NED;                    // V fragment-order [96][16][4096]
    short* Op  = Vp + NED;
    short* qb  = Op + NED;                    // bf16 inputs
    short* kb  = qb + NED;
    short* vb  = kb + NED;
    short* Wqb = vb + NED;                    // bf16 weights
    short* Wkb = Wqb + WED;
    short* Wvb = Wkb + WED;
    short* Wob = Wvb + WED;

    const dim3 blk(256);

    cvt_all<<<2048, blk, 0, stream>>>(q, k, v, Wq, Wk, Wv, Wo,
                                      qb, kb, vb, Wqb, Wkb, Wvb, Wob,
                                      (int)(NED / 8), (int)(WED / 8));

    const int gemm_grid = (MROWS / 128) * (DIM / 128);   // 384
    gemm_qkv<<<3 * gemm_grid, blk, 0, stream>>>(qb, kb, vb, Wqb, Wkb, Wvb,
                                                bq, bk, bv, Qp, Kp, Vp);

    const int attn_grid = BATCH * NHEAD * (SEQ / 64);    // 1536
    attn_kernel<<<attn_grid, blk, 0, stream>>>(Qp, Kp, Vp, attn_bias, attn_mask, Op);

    gemm_out<<<gemm_grid, blk, 0, stream>>>(Op, Wob, bo, out);
}

// Round 18
// 251.742 us; speedup vs baseline: 1.2018x; 1.2018x over previous
//
#include <hip/hip_runtime.h>
#include <hip/hip_bf16.h>

using f32x4  = __attribute__((ext_vector_type(4))) float;
using i32x4  = __attribute__((ext_vector_type(4))) int;
using bf16x8 = __attribute__((ext_vector_type(8))) short;
using bf16x4 = __attribute__((ext_vector_type(4))) short;

constexpr int BATCH = 8, SEQ = 1024, DIM = 768, NHEAD = 12, HDIM = 64;
constexpr int MROWS = BATCH * SEQ;   // 8192

__device__ __forceinline__ short f2bf(float f) {
    union { float f; unsigned u; } x; x.f = f;
    unsigned r = (x.u + 0x7fffu + ((x.u >> 16) & 1u)) >> 16;
    return (short)r;
}
__device__ __forceinline__ float fexp2(float x) { return __builtin_amdgcn_exp2f(x); }

// async global->LDS, 16B per lane; LDS dest = wave-uniform base + lane*16
__device__ __forceinline__ void gload_lds16(const void* g, void* l) {
    __builtin_amdgcn_global_load_lds(
        (const __attribute__((address_space(1))) void*)g,
        (__attribute__((address_space(3))) void*)l, 16, 0, 0);
}

__device__ __forceinline__ bf16x8 cvt8(const float* p) {
    const f32x4 x0 = *(const f32x4*)p;
    const f32x4 x1 = *(const f32x4*)(p + 4);
    bf16x8 r;
    #pragma unroll
    for (int j = 0; j < 4; ++j) { r[j] = f2bf(x0[j]); r[4 + j] = f2bf(x1[j]); }
    return r;
}

// K fragment-order: attn reads kb[c][ks] at kt*4096 + c*1024 + ks*512 + lane*8
__device__ __forceinline__ long kfrag_addr(int tok, int dd) {
    return ((long)(tok >> 6)) * 4096 + ((tok & 63) >> 4) * 1024 + (dd >> 5) * 512
         + ((dd >> 3) & 3) * 128 + (tok & 15) * 8 + (dd & 7);
}
// V fragment-order: attn reads vb[df][ks] at kt*4096 + df*1024 + ks*512 + lane*8
__device__ __forceinline__ long vfrag_addr(int tok, int dd) {
    return ((long)(tok >> 6)) * 4096 + (dd >> 4) * 1024 + ((tok >> 5) & 1) * 512
         + ((tok >> 3) & 3) * 128 + (dd & 15) * 8 + (tok & 7);
}

// single fp32->bf16 prepass: 3 big arrays + 4 weight arrays in one launch
__global__ __launch_bounds__(256)
void cvt_all(const float* __restrict__ q, const float* __restrict__ k,
             const float* __restrict__ v,
             const float* __restrict__ Wq, const float* __restrict__ Wk,
             const float* __restrict__ Wv, const float* __restrict__ Wo,
             short* __restrict__ qb, short* __restrict__ kb, short* __restrict__ vb,
             short* __restrict__ Wqb, short* __restrict__ Wkb,
             short* __restrict__ Wvb, short* __restrict__ Wob,
             int nbig8, int nsml8) {
    const int stride = gridDim.x * 256;
    for (int i = blockIdx.x * 256 + threadIdx.x; i < nbig8; i += stride) {
        const long base = (long)i * 8;
        *(bf16x8*)(qb + base) = cvt8(q + base);
        *(bf16x8*)(kb + base) = cvt8(k + base);
        *(bf16x8*)(vb + base) = cvt8(v + base);
    }
    for (int i = blockIdx.x * 256 + threadIdx.x; i < nsml8; i += stride) {
        const long base = (long)i * 8;
        *(bf16x8*)(Wqb + base) = cvt8(Wq + base);
        *(bf16x8*)(Wkb + base) = cvt8(Wk + base);
        *(bf16x8*)(Wvb + base) = cvt8(Wv + base);
        *(bf16x8*)(Wob + base) = cvt8(Wo + base);
    }
}

// Fused Q/K/V projection: 128x128 tile, global_load_lds width=16,
// linear LDS [128][32], 2 barriers per K-step. sub = bid%3 interleave.
__global__ __launch_bounds__(256, 4)
void gemm_qkv(const short* __restrict__ qb, const short* __restrict__ kb,
              const short* __restrict__ vbp,
              const short* __restrict__ Wqb, const short* __restrict__ Wkb,
              const short* __restrict__ Wvb,
              const float* __restrict__ bq, const float* __restrict__ bk,
              const float* __restrict__ bv,
              short* __restrict__ Qp, short* __restrict__ Kp, short* __restrict__ Vp) {
    constexpr int K  = DIM;
    constexpr int NT = DIM / 128;
    __shared__ alignas(16) short As[128][32];
    __shared__ alignas(16) short Bs[128][32];

    const int sub = blockIdx.x % 3;
    const int bid = blockIdx.x / 3;
    const short* A = sub == 0 ? qb : sub == 1 ? kb : vbp;
    const short* W = sub == 0 ? Wqb : sub == 1 ? Wkb : Wvb;
    const float* bias = sub == 0 ? bq : sub == 1 ? bk : bv;

    const int bm = bid / NT, bn = bid % NT;
    const int m0 = bm * 128, n0 = bn * 128;
    const int t = threadIdx.x;
    const int lane = t & 63, w = t >> 6;
    const int wm = (w >> 1) * 64, wn = (w & 1) * 64;
    const int l16 = lane & 15, lg = lane >> 4;

    const int lrow = lane >> 2, lcol = (lane & 3) * 8;
    const short* ag = A + (long)(m0 + w * 32 + lrow) * K + lcol;
    const short* wg = W + (long)(n0 + w * 32 + lrow) * K + lcol;
    short* lA0 = &As[w * 32][0];
    short* lA1 = &As[w * 32 + 16][0];
    short* lB0 = &Bs[w * 32][0];
    short* lB1 = &Bs[w * 32 + 16][0];

    f32x4 acc[4][4] = {};

    for (int k0 = 0; k0 < K; k0 += 32) {
        gload_lds16(ag + k0, lA0);
        gload_lds16(ag + (long)16 * K + k0, lA1);
        gload_lds16(wg + k0, lB0);
        gload_lds16(wg + (long)16 * K + k0, lB1);
        __syncthreads();   // vmcnt(0) drain + all waves staged

        bf16x8 af[4], bfg[4];
        const int kc = lg * 8;
        #pragma unroll
        for (int mi = 0; mi < 4; ++mi)
            af[mi] = *(const bf16x8*)&As[wm + mi * 16 + l16][kc];
        #pragma unroll
        for (int ni = 0; ni < 4; ++ni)
            bfg[ni] = *(const bf16x8*)&Bs[wn + ni * 16 + l16][kc];
        #pragma unroll
        for (int mi = 0; mi < 4; ++mi)
            #pragma unroll
            for (int ni = 0; ni < 4; ++ni)
                acc[mi][ni] = __builtin_amdgcn_mfma_f32_16x16x32_bf16(
                    af[mi], bfg[ni], acc[mi][ni], 0, 0, 0);
        __syncthreads();   // compute done before next stage overwrites
    }

    #pragma unroll
    for (int mi = 0; mi < 4; ++mi) {
        const int row = m0 + wm + mi * 16 + lg * 4;
        const int bb = row / SEQ;
        #pragma unroll
        for (int ni = 0; ni < 4; ++ni) {
            const int col = n0 + wn + ni * 16 + l16;
            const float bv = bias[col];
            const int hh = col >> 6, dd = col & 63;
            #pragma unroll
            for (int j = 0; j < 4; ++j) {
                float val = acc[mi][ni][j] + bv;
                if (sub == 0) {
                    Qp[(long)(row + j) * DIM + col] = f2bf(val * 0.125f);
                } else {
                    const int tok = (row % SEQ) + j;
                    const long pbase = (long)(bb * NHEAD + hh) * 65536;
                    if (sub == 1)
                        Kp[pbase + kfrag_addr(tok, dd)] = f2bf(val);
                    else
                        Vp[pbase + vfrag_addr(tok, dd)] = f2bf(val);
                }
            }
        }
    }
}

// Output projection, same m97-style staging. C fp32 = A(bf16) @ W^T + bias
__global__ __launch_bounds__(256, 4)
void gemm_out(const short* __restrict__ A, const short* __restrict__ W,
              const float* __restrict__ bias, float* __restrict__ Cout) {
    constexpr int K  = DIM;
    constexpr int NT = DIM / 128;
    __shared__ alignas(16) short As[128][32];
    __shared__ alignas(16) short Bs[128][32];

    const int bm = blockIdx.x / NT, bn = blockIdx.x % NT;
    const int m0 = bm * 128, n0 = bn * 128;
    const int t = threadIdx.x;
    const int lane = t & 63, w = t >> 6;
    const int wm = (w >> 1) * 64, wn = (w & 1) * 64;
    const int l16 = lane & 15, lg = lane >> 4;

    const int lrow = lane >> 2, lcol = (lane & 3) * 8;
    const short* ag = A + (long)(m0 + w * 32 + lrow) * K + lcol;
    const short* wg = W + (long)(n0 + w * 32 + lrow) * K + lcol;
    short* lA0 = &As[w * 32][0];
    short* lA1 = &As[w * 32 + 16][0];
    short* lB0 = &Bs[w * 32][0];
    short* lB1 = &Bs[w * 32 + 16][0];

    f32x4 acc[4][4] = {};

    for (int k0 = 0; k0 < K; k0 += 32) {
        gload_lds16(ag + k0, lA0);
        gload_lds16(ag + (long)16 * K + k0, lA1);
        gload_lds16(wg + k0, lB0);
        gload_lds16(wg + (long)16 * K + k0, lB1);
        __syncthreads();

        bf16x8 af[4], bfg[4];
        const int kc = lg * 8;
        #pragma unroll
        for (int mi = 0; mi < 4; ++mi)
            af[mi] = *(const bf16x8*)&As[wm + mi * 16 + l16][kc];
        #pragma unroll
        for (int ni = 0; ni < 4; ++ni)
            bfg[ni] = *(const bf16x8*)&Bs[wn + ni * 16 + l16][kc];
        #pragma unroll
        for (int mi = 0; mi < 4; ++mi)
            #pragma unroll
            for (int ni = 0; ni < 4; ++ni)
                acc[mi][ni] = __builtin_amdgcn_mfma_f32_16x16x32_bf16(
                    af[mi], bfg[ni], acc[mi][ni], 0, 0, 0);
        __syncthreads();
    }

    #pragma unroll
    for (int mi = 0; mi < 4; ++mi) {
        const int row = m0 + wm + mi * 16 + lg * 4;
        #pragma unroll
        for (int ni = 0; ni < 4; ++ni) {
            const int col = n0 + wn + ni * 16 + l16;
            const float bv = bias[col];
            #pragma unroll
            for (int j = 0; j < 4; ++j)
                Cout[(long)(row + j) * DIM + col] = acc[mi][ni][j] + bv;
        }
    }
}

// Flash attention (round-13 best): fragment-ordered K/V direct loads,
// double-buffered masked-bias LDS, P aliased into CUR rows, T13 defer-max.
__global__ __launch_bounds__(256, 4)
void attn_kernel(const short* __restrict__ Qp, const short* __restrict__ Kt,
                 const short* __restrict__ Vt, const float* __restrict__ bias,
                 const int* __restrict__ mask, short* __restrict__ Op) {
    __shared__ float Bsm[2][64][68];   // 34.8 KB

    const int d = blockIdx.x;
    const int lgc = (d & 7) * 192 + (d >> 3);   // XCD-contiguous (b,h) pairs
    const int qt = lgc & 15, pair = lgc >> 4;
    const int h = pair % NHEAD, b = pair / NHEAD;

    const int t = threadIdx.x, lane = t & 63, w = t >> 6;
    const int l16 = lane & 15, lg = lane >> 4;
    const int ql = w * 16 + l16;

    const int qrow = qt * 64 + ql;
    const short* qptr = Qp + (long)(b * SEQ + qrow) * DIM + h * HDIM + lg * 8;
    const bf16x8 qf0 = *(const bf16x8*)qptr;
    const bf16x8 qf1 = *(const bf16x8*)(qptr + 32);

    const short* ktile = Kt + (long)pair * 65536 + lane * 8;
    const short* vtile = Vt + (long)pair * 65536 + lane * 8;

    const int srow = t >> 4, scol = (t & 15) * 4;
    const float* bst = bias + ((long)pair * SEQ + qt * 64 + srow) * SEQ + scol;
    const int*   mst = mask + ((long)b * SEQ + qt * 64 + srow) * SEQ + scol;

    f32x4 acc_o[4] = {};
    float m_run = -1e30f, l_run = 0.f;
    constexpr float L2E = 1.4426950408889634f;

    f32x4 br[4]; i32x4 mr[4];

    auto issue_bm = [&](int kt) {
        #pragma unroll
        for (int i = 0; i < 4; ++i) {
            br[i] = __builtin_nontemporal_load((const f32x4*)(bst + (long)i * 16 * SEQ + kt * 64));
            mr[i] = *(const i32x4*)(mst + (long)i * 16 * SEQ + kt * 64);
        }
    };
    auto write_bm = [&](int buf) {
        #pragma unroll
        for (int i = 0; i < 4; ++i) {
            f32x4 o;
            #pragma unroll
            for (int j = 0; j < 4; ++j) o[j] = mr[i][j] ? br[i][j] : -1e30f;
            *(f32x4*)&Bsm[buf][i * 16 + srow][scol] = o;
        }
    };

    auto compute = [&](int kt, int buf) {
        const short* kf = ktile + kt * 4096;
        const short* vf = vtile + kt * 4096;
        short* prow = (short*)&Bsm[buf][ql][0];   // wave-private row in CUR buffer

        f32x4 s[4];
        __builtin_amdgcn_s_setprio(1);
        #pragma unroll
        for (int c = 0; c < 4; ++c) {
            const bf16x8 kb = *(const bf16x8*)(kf + c * 1024);
            f32x4 ci = *(const f32x4*)&Bsm[buf][ql][c * 16 + lg * 4];
            s[c] = __builtin_amdgcn_mfma_f32_16x16x32_bf16(kb, qf0, ci, 0, 0, 0);
        }
        #pragma unroll
        for (int c = 0; c < 4; ++c) {
            const bf16x8 kb = *(const bf16x8*)(kf + c * 1024 + 512);
            s[c] = __builtin_amdgcn_mfma_f32_16x16x32_bf16(kb, qf1, s[c], 0, 0, 0);
        }
        __builtin_amdgcn_s_setprio(0);

        float mt = -1e30f;
        #pragma unroll
        for (int c = 0; c < 4; ++c)
            #pragma unroll
            for (int j = 0; j < 4; ++j)
                mt = fmaxf(mt, s[c][j]);
        mt = fmaxf(mt, __shfl_xor(mt, 16));
        mt = fmaxf(mt, __shfl_xor(mt, 32));

        // T13 defer-max: only rescale when the max moved by more than 8
        if (!__all(mt - m_run <= 8.f)) {
            const float mn = fmaxf(m_run, mt);
            const float alpha = fexp2((m_run - mn) * L2E);
            m_run = mn;
            float al[4];
            #pragma unroll
            for (int j = 0; j < 4; ++j) al[j] = __shfl(alpha, lg * 4 + j);
            #pragma unroll
            for (int df = 0; df < 4; ++df)
                #pragma unroll
                for (int j = 0; j < 4; ++j)
                    acc_o[df][j] *= al[j];
            l_run *= alpha;
        }
        const float nm = -m_run * L2E;

        float lt = 0.f;
        #pragma unroll
        for (int c = 0; c < 4; ++c) {
            bf16x4 pk;
            #pragma unroll
            for (int j = 0; j < 4; ++j) {
                const float e = fexp2(fmaf(s[c][j], L2E, nm));
                lt += e;
                pk[j] = f2bf(e);
            }
            *(bf16x4*)(prow + c * 16 + lg * 4) = pk;
        }
        lt += __shfl_xor(lt, 16);
        lt += __shfl_xor(lt, 32);
        l_run += lt;

        const bf16x8 pa0 = *(const bf16x8*)(prow + lg * 8);
        const bf16x8 pa1 = *(const bf16x8*)(prow + 32 + lg * 8);
        __builtin_amdgcn_s_setprio(1);
        #pragma unroll
        for (int df = 0; df < 4; ++df) {
            const bf16x8 vb = *(const bf16x8*)(vf + df * 1024);
            acc_o[df] = __builtin_amdgcn_mfma_f32_16x16x32_bf16(pa0, vb, acc_o[df], 0, 0, 0);
        }
        #pragma unroll
        for (int df = 0; df < 4; ++df) {
            const bf16x8 vb = *(const bf16x8*)(vf + df * 1024 + 512);
            acc_o[df] = __builtin_amdgcn_mfma_f32_16x16x32_bf16(pa1, vb, acc_o[df], 0, 0, 0);
        }
        __builtin_amdgcn_s_setprio(0);
    };

    // prologue: tile 0 into buf0; tile 1 loads in flight
    issue_bm(0);
    write_bm(0);
    issue_bm(1);
    __syncthreads();

    int cur = 0;
    for (int kt = 0; kt < 16; ++kt) {
        compute(kt, cur);
        if (kt < 15) {
            write_bm(cur ^ 1);              // regs for kt+1 (issued a full iter ago)
            if (kt < 14) issue_bm(kt + 2);  // next-next: full-iter + barrier cover
            __syncthreads();
            cur ^= 1;
        }
    }

    float linv[4];
    #pragma unroll
    for (int j = 0; j < 4; ++j)
        linv[j] = 1.f / fmaxf(__shfl(l_run, lg * 4 + j), 1e-20f);

    #pragma unroll
    for (int df = 0; df < 4; ++df) {
        #pragma unroll
        for (int j = 0; j < 4; ++j) {
            const float val = acc_o[df][j] * linv[j];
            const int row = b * SEQ + qt * 64 + w * 16 + lg * 4 + j;
            const int col = h * HDIM + df * 16 + l16;
            Op[(long)row * DIM + col] = f2bf(val);
        }
    }
}

extern "C" void kernel_launch(void* const* d_in, const int* in_sizes, int n_in,
                              void* d_out, int out_size, void* d_ws, size_t ws_size,
                              hipStream_t stream) {
    const float* q         = (const float*)d_in[0];
    const float* k         = (const float*)d_in[1];
    const float* v         = (const float*)d_in[2];
    const float* attn_bias = (const float*)d_in[3];
    const int*   attn_mask = (const int*)d_in[4];
    const float* Wq = (const float*)d_in[5];
    const float* bq = (const float*)d_in[6];
    const float* Wk = (const float*)d_in[7];
    const float* bk = (const float*)d_in[8];
    const float* Wv = (const float*)d_in[9];
    const float* bv = (const float*)d_in[10];
    const float* Wo = (const float*)d_in[11];
    const float* bo = (const float*)d_in[12];
    float* out = (float*)d_out;

    const long NED = (long)MROWS * DIM;       // 6291456
    const long WED = (long)DIM * DIM;         // 589824
    short* Qp  = (short*)d_ws;                // [8192][768] bf16, pre-scaled 1/8
    short* Kp  = Qp + NED;                    // K fragment-order [96][16][4096]
    short* Vp  = Kp + NED;                    // V fragment-order [96][16][4096]
    short* Op  = Vp + NED;
    short* qb  = Op + NED;                    // bf16 inputs
    short* kb  = qb + NED;
    short* vb  = kb + NED;
    short* Wqb = vb + NED;                    // bf16 weights
    short* Wkb = Wqb + WED;
    short* Wvb = Wkb + WED;
    short* Wob = Wvb + WED;

    const dim3 blk(256);

    cvt_all<<<2048, blk, 0, stream>>>(q, k, v, Wq, Wk, Wv, Wo,
                                      qb, kb, vb, Wqb, Wkb, Wvb, Wob,
                                      (int)(NED / 8), (int)(WED / 8));

    const int gemm_grid = (MROWS / 128) * (DIM / 128);   // 384
    gemm_qkv<<<3 * gemm_grid, blk, 0, stream>>>(qb, kb, vb, Wqb, Wkb, Wvb,
                                                bq, bk, bv, Qp, Kp, Vp);

    const int attn_grid = BATCH * NHEAD * (SEQ / 64);    // 1536
    attn_kernel<<<attn_grid, blk, 0, stream>>>(Qp, Kp, Vp, attn_bias, attn_mask, Op);

    gemm_out<<<gemm_grid, blk, 0, stream>>>(Op, Wob, bo, out);
}